// Round 15
// baseline (831.484 us; speedup 1.0000x reference)
//
#include <hip/hip_runtime.h>
#include <cstdint>
#include <cstddef>

#define NN 100000
#define EE 1600000
#define XDIM 1553
#define HD 128

typedef __attribute__((ext_vector_type(8))) short short8;
typedef __attribute__((ext_vector_type(4))) float f32x4;
// unaligned-capable 4-float vector: hardware allows 4B-aligned dwordx4
typedef float f32x4u __attribute__((vector_size(16), aligned(4)));

union Frag { unsigned int u[4]; short8 s; uint4 v; };

// weight area offsets (ushort units); hi/lo are separate regions
#define OFF_DES_HI 0
#define OFF_DES_LO 98304
#define OFF_TW_HI  196608
#define OFF_TW_LO  294912
#define OFF_NUM_HI 393216
#define OFF_NUM_LO 397312
#define OFF_CAT_HI 401408
#define OFF_CAT_LO 405504
#define OFF_WIN_HI 409600
#define OFF_WIN_LO 475136
#define OFF_L1_HI  540672
#define OFF_L1_LO  589824
#define OFF_L2_HI  638976
#define OFF_L2_LO  688128
#define WT_SITES   385024   // (col,k) sites (L2/CLS ranges skipped: fusew owns L2)

#define PREPW_BLOCKS 1504   // WT_SITES / 256
#define COUNT_BLOCKS 6250   // EE / 256
#define FUSEW_BLOCKS 193    // 2 fused-k rows per block (k = 0..385, 385 valid+bias)
#define NBLK64       1563   // (NN + 63) / 64   (rgemm2 grid)
#define PROJ128_NBLK 782    // (NN + 127) / 128 (proj grid)
#define FILL_BLOCKS  6250   // EE / 256

// hi = trunc-bf16(f), lo = trunc-bf16(f - hi). Packed: 2 elems -> 1 u32 via v_perm.
__device__ __forceinline__ void cvt_pair(float f0, float f1,
                                         unsigned int& hi, unsigned int& lo) {
  unsigned int u0 = __float_as_uint(f0), u1 = __float_as_uint(f1);
  hi = __builtin_amdgcn_perm(u1, u0, 0x07060302u);
  float l0 = f0 - __uint_as_float(u0 & 0xFFFF0000u);
  float l1 = f1 - __uint_as_float(u1 & 0xFFFF0000u);
  lo = __builtin_amdgcn_perm(__float_as_uint(l1), __float_as_uint(l0), 0x07060302u);
}

// round-to-nearest-even bf16
__device__ __forceinline__ unsigned short bf16_rne(float f) {
  unsigned int u = __float_as_uint(f);
  return (unsigned short)((u + 0x7FFFu + ((u >> 16) & 1u)) >> 16);
}

// raw barriers: no vmcnt drain (prefetched global loads ride across);
// lgkm0 variant publishes ds_writes before the barrier.
__device__ __forceinline__ void fence_barrier() {
  asm volatile("" ::: "memory");
  __builtin_amdgcn_s_barrier();
  asm volatile("" ::: "memory");
}
__device__ __forceinline__ void lgkm0_barrier() {
  asm volatile("s_waitcnt lgkmcnt(0)" ::: "memory");
  __builtin_amdgcn_s_barrier();
  asm volatile("" ::: "memory");
}

// ---------------- setup: weight pre-convert + edge count + classifier fusion ----
// blocks [0, PREPW): transpose/split weights (L2/CLS ranges skipped — dead since
// classifier fusion; fusew owns OFF_L2). blocks [PREPW, PREPW+COUNT): edge count
// atomics. blocks [PREPW+COUNT, +FUSEW): Wfused = [root2;rel2]@Wcls into OFF_L2
// (reads original inputs only -> no race with prepw). One launch for all three.
__global__ __launch_bounds__(256) void k_setup(
    const float* __restrict__ Wdes, const float* __restrict__ Wtw,
    const float* __restrict__ Wnum, const float* __restrict__ Wcat,
    const float* __restrict__ Win,  const float* __restrict__ root1,
    const float* __restrict__ rel1, const float* __restrict__ root2,
    const float* __restrict__ rel2, const float* __restrict__ Wcls,
    unsigned short* __restrict__ Wt,
    const int* __restrict__ ei, const int* __restrict__ et,
    int* __restrict__ cnt2,
    const float* __restrict__ bias2, const float* __restrict__ bcls,
    float* __restrict__ bfused) {
  if (blockIdx.x >= PREPW_BLOCKS + COUNT_BLOCKS) {
    // classifier fusion
    int fb = blockIdx.x - (PREPW_BLOCKS + COUNT_BLOCKS);
    int k = fb * 2 + (threadIdx.x >> 7);
    int c = threadIdx.x & 127;
    if (k > 384) return;
    const float* wrow;
    if (k < 128)      wrow = root2 + (size_t)k * 128;
    else if (k < 256) wrow = rel2 + (size_t)(k - 128) * 128;
    else if (k < 384) wrow = rel2 + 16384 + (size_t)(k - 256) * 128;
    else              wrow = bias2;
    float s = 0.f;
    for (int j = 0; j < 128; ++j) s += wrow[j] * Wcls[(size_t)j * 128 + c];
    if (k == 384) { bfused[c] = s + bcls[c]; return; }
    unsigned int u = __float_as_uint(s);
    float lo = s - __uint_as_float(u & 0xFFFF0000u);
    int sub = k >> 7, kl = k & 127;
    Wt[OFF_L2_HI + sub * 16384 + c * 128 + kl] = (unsigned short)(u >> 16);
    Wt[OFF_L2_LO + sub * 16384 + c * 128 + kl] = (unsigned short)(__float_as_uint(lo) >> 16);
    return;
  }
  if (blockIdx.x >= PREPW_BLOCKS) {
    int e = (blockIdx.x - PREPW_BLOCKS) * 256 + threadIdx.x;
    if (e < EE) atomicAdd(&cnt2[et[e] * NN + ei[EE + e]], 1);
    return;
  }
  int id = blockIdx.x * 256 + threadIdx.x;
  if (id >= 319488) return;   // root2/rel2/Wcls sites dead (fusew owns OFF_L2)
  const float* src; int K, Kpad, dhi, dlo, local;
  if (id < 98304)       { src=Wdes;        K=768; Kpad=768; dhi=OFF_DES_HI;       dlo=OFF_DES_LO;       local=id; }
  else if (id < 196608) { src=Wtw;         K=768; Kpad=768; dhi=OFF_TW_HI;        dlo=OFF_TW_LO;        local=id-98304; }
  else if (id < 200704) { src=Wnum;        K=6;   Kpad=32;  dhi=OFF_NUM_HI;       dlo=OFF_NUM_LO;       local=id-196608; }
  else if (id < 204800) { src=Wcat;        K=11;  Kpad=32;  dhi=OFF_CAT_HI;       dlo=OFF_CAT_LO;       local=id-200704; }
  else if (id < 270336) { src=Win;         K=512; Kpad=512; dhi=OFF_WIN_HI;       dlo=OFF_WIN_LO;       local=id-204800; }
  else if (id < 286720) { src=root1;       K=128; Kpad=128; dhi=OFF_L1_HI;        dlo=OFF_L1_LO;        local=id-270336; }
  else if (id < 303104) { src=rel1;        K=128; Kpad=128; dhi=OFF_L1_HI+16384;  dlo=OFF_L1_LO+16384;  local=id-286720; }
  else                  { src=rel1+16384;  K=128; Kpad=128; dhi=OFF_L1_HI+32768;  dlo=OFF_L1_LO+32768;  local=id-303104; }
  int col = local / Kpad;
  int k = local - col * Kpad;
  float v = (k < K) ? src[(size_t)k * 128 + col] : 0.f;
  unsigned int u = __float_as_uint(v);
  float lo = v - __uint_as_float(u & 0xFFFF0000u);
  Wt[dhi + col * Kpad + k] = (unsigned short)(u >> 16);
  Wt[dlo + col * Kpad + k] = (unsigned short)(__float_as_uint(lo) >> 16);
}

// ---------------- CSR scans ----------------
__global__ __launch_bounds__(256) void k_scan1(const int* __restrict__ cnt2,
                                               int* __restrict__ row_ptr,
                                               int* __restrict__ bsum) {
  __shared__ int sums[256];
  int t = threadIdx.x;
  int base = blockIdx.x * 1024 + t * 4;
  int v[4]; int s = 0;
#pragma unroll
  for (int j = 0; j < 4; ++j) {
    int idx = base + j;
    v[j] = (idx < NN) ? (cnt2[idx] + cnt2[NN + idx]) : 0;
    s += v[j];
  }
  sums[t] = s;
  __syncthreads();
  for (int d = 1; d < 256; d <<= 1) {
    int val = (t >= d) ? sums[t - d] : 0;
    __syncthreads();
    sums[t] += val;
    __syncthreads();
  }
  int excl = sums[t] - s;
  if (t == 255) bsum[blockIdx.x] = sums[t];
  int run = excl;
#pragma unroll
  for (int j = 0; j < 4; ++j) {
    int idx = base + j;
    if (idx < NN) row_ptr[idx] = run;
    run += v[j];
  }
}

__global__ __launch_bounds__(128) void k_scan2(int* __restrict__ bsum, int nb) {
  __shared__ int s[128];
  int t = threadIdx.x;
  int v = (t < nb) ? bsum[t] : 0;
  s[t] = v;
  __syncthreads();
  for (int d = 1; d < 128; d <<= 1) {
    int val = (t >= d) ? s[t - d] : 0;
    __syncthreads();
    s[t] += val;
    __syncthreads();
  }
  if (t < nb) bsum[t] = s[t] - v;
}

__global__ __launch_bounds__(256) void k_scan3(int* __restrict__ row_ptr,
                                               const int* __restrict__ bsum) {
  int idx = blockIdx.x * 256 + threadIdx.x;
  if (idx < NN) row_ptr[idx] += bsum[idx >> 10];
  if (idx == NN) row_ptr[NN] = EE;
}

// ---------------- fused projection + CSR fill (MFMA, split-bf16, raw barriers) ---
// Blocks 0..781: 128 nodes/block, 4 waves, wave = 32 rows (2 subs) x 128 cols.
// Blocks >= 782: CSR fill. Epilogue emits h0 (f32) + h16 (bf16). s_setprio(1)
// wraps MFMA clusters: 2 independent blocks/CU drift out of phase, so the
// MFMA-issuing block preempts the staging block (T5 role-diversity regime).
__global__ __launch_bounds__(256, 2) void k_proj2(
    const float* __restrict__ x,
    const float* __restrict__ bdes, const float* __restrict__ btw,
    const float* __restrict__ bnum, const float* __restrict__ bcat,
    const float* __restrict__ bin,  const float* __restrict__ pa,
    const unsigned short* __restrict__ Wt, float* __restrict__ h0,
    unsigned short* __restrict__ h16,
    const int* __restrict__ ei, const int* __restrict__ et,
    const int* __restrict__ row_ptr, int* __restrict__ fillpos,
    int* __restrict__ entries) {
  __shared__ unsigned short bt_hi[128 * 32], bt_lo[128 * 32];   // 8KB + 8KB
  __shared__ unsigned short z_hi[128 * 128], z_lo[128 * 128];   // 32KB + 32KB

  if (blockIdx.x >= PROJ128_NBLK) {
    int e = (blockIdx.x - PROJ128_NBLK) * 256 + threadIdx.x;
    if (e < EE) {
      int src = ei[e];
      int dst = ei[EE + e];
      int r = et[e];
      int pos = atomicAdd(&fillpos[dst], 1);
      entries[row_ptr[dst] + pos] = src | (r << 20);
    }
    return;
  }

  const int t = threadIdx.x;
  const int node0 = blockIdx.x * 128;
  const int w = t >> 6, lane = t & 63;
  const int li = lane & 15, lg = lane >> 4;

  // B-staging constants (loop-invariant per thread)
  const int cr0 = t >> 2, c0 = t & 3;
  const int cr1 = cr0 + 64;
  const unsigned stb0 = cr0 * 64 + ((c0 ^ ((cr0 >> 1) & 3)) << 4);
  const unsigned stb1 = cr1 * 64 + ((c0 ^ ((cr1 >> 1) & 3)) << 4);

  // two A-rows per (wave, li): sub0 = w*32+li, sub1 = +16
  const int rowA0 = w * 32 + li;
  const int rowA1 = rowA0 + 16;
  int nodeA0 = node0 + rowA0; int nd0 = nodeA0 < NN ? nodeA0 : NN - 1;
  int nodeA1 = node0 + rowA1; int nd1 = nodeA1 < NN ? nodeA1 : NN - 1;
  const float* xrow0 = x + (size_t)nd0 * XDIM;
  const float* xrow1 = x + (size_t)nd1 * XDIM;

#define STORE_BT(SH0, SL0, SH1, SL1)              \
  do {                                            \
    *(uint4*)((char*)bt_hi + stb0) = (SH0);       \
    *(uint4*)((char*)bt_lo + stb0) = (SL0);       \
    *(uint4*)((char*)bt_hi + stb1) = (SH1);       \
    *(uint4*)((char*)bt_lo + stb1) = (SL1);       \
  } while (0)

#define CVT_A2(FA, FB, AH, AL)                                                   \
  do {                                                                           \
    cvt_pair((FA)[0], (FA)[1], (AH).u[0], (AL).u[0]);                            \
    cvt_pair((FA)[2], (FA)[3], (AH).u[1], (AL).u[1]);                            \
    cvt_pair((FB)[0], (FB)[1], (AH).u[2], (AL).u[2]);                            \
    cvt_pair((FB)[2], (FB)[3], (AH).u[3], (AL).u[3]);                            \
  } while (0)

// 8 col-tiles; B frags read ONCE, used by both subs. setprio(1) keeps this
// block's matrix pipe fed while the co-resident block stages.
#define MFMA8_2(A0H, A0L, A1H, A1L, ACC)                                         \
  do {                                                                           \
    __builtin_amdgcn_s_setprio(1);                                               \
    _Pragma("unroll")                                                            \
    for (int ct_ = 0; ct_ < 8; ++ct_) {                                          \
      int colrow_ = ct_ * 16 + li;                                               \
      int byte_ = colrow_ * 64 + (lg << 4);                                      \
      byte_ ^= ((colrow_ >> 1) & 3) << 4;                                        \
      Frag bh_, bl_;                                                             \
      bh_.v = *(const uint4*)((char*)bt_hi + byte_);                             \
      bl_.v = *(const uint4*)((char*)bt_lo + byte_);                             \
      (ACC)[0][ct_] = __builtin_amdgcn_mfma_f32_16x16x32_bf16((A0H).s, bl_.s, (ACC)[0][ct_], 0, 0, 0); \
      (ACC)[0][ct_] = __builtin_amdgcn_mfma_f32_16x16x32_bf16((A0L).s, bh_.s, (ACC)[0][ct_], 0, 0, 0); \
      (ACC)[0][ct_] = __builtin_amdgcn_mfma_f32_16x16x32_bf16((A0H).s, bh_.s, (ACC)[0][ct_], 0, 0, 0); \
      (ACC)[1][ct_] = __builtin_amdgcn_mfma_f32_16x16x32_bf16((A1H).s, bl_.s, (ACC)[1][ct_], 0, 0, 0); \
      (ACC)[1][ct_] = __builtin_amdgcn_mfma_f32_16x16x32_bf16((A1L).s, bh_.s, (ACC)[1][ct_], 0, 0, 0); \
      (ACC)[1][ct_] = __builtin_amdgcn_mfma_f32_16x16x32_bf16((A1H).s, bh_.s, (ACC)[1][ct_], 0, 0, 0); \
    }                                                                            \
    __builtin_amdgcn_s_setprio(0);                                               \
  } while (0)

#define TILE(WC0, WC1, WC2, WC3, WN0, WN1, WN2, WN3, XA0, XB0, XA1, XB1, T)      \
  do {                                                                           \
    STORE_BT(WC0, WC1, WC2, WC3);                                                \
    lgkm0_barrier();                                                             \
    Frag a0h_, a0l_, a1h_, a1l_;                                                 \
    CVT_A2(XA0, XB0, a0h_, a0l_);                                                \
    CVT_A2(XA1, XB1, a1h_, a1l_);                                                \
    {                                                                            \
      const int kw_ = ((T) + 1) * 32;                                            \
      WN0 = *(const uint4*)(ph0 + kw_); WN1 = *(const uint4*)(pl0 + kw_);        \
      WN2 = *(const uint4*)(ph1 + kw_); WN3 = *(const uint4*)(pl1 + kw_);        \
      int kx_ = (T) + 2; if (kx_ > 23) kx_ = 23; kx_ *= 32;                      \
      XA0 = *(const f32x4u*)(xr0 + kx_);                                         \
      XB0 = *(const f32x4u*)(xr0 + kx_ + 4);                                     \
      XA1 = *(const f32x4u*)(xr1 + kx_);                                         \
      XB1 = *(const f32x4u*)(xr1 + kx_ + 4);                                     \
    }                                                                            \
    MFMA8_2(a0h_, a0l_, a1h_, a1l_, zacc);                                       \
    fence_barrier();                                                             \
  } while (0)

#define MFMA_B(KT)                                                               \
  do {                                                                           \
    Frag a0h_, a0l_, a1h_, a1l_;                                                 \
    {                                                                            \
      int byte0_ = rowA0 * 256 + (((KT) * 32 + lg * 8) << 1);                    \
      byte0_ ^= (rowA0 & 7) << 4;                                                \
      a0h_.v = *(const uint4*)((char*)z_hi + byte0_);                            \
      a0l_.v = *(const uint4*)((char*)z_lo + byte0_);                            \
      int byte1_ = rowA1 * 256 + (((KT) * 32 + lg * 8) << 1);                    \
      byte1_ ^= (rowA1 & 7) << 4;                                                \
      a1h_.v = *(const uint4*)((char*)z_hi + byte1_);                            \
      a1l_.v = *(const uint4*)((char*)z_lo + byte1_);                            \
    }                                                                            \
    MFMA8_2(a0h_, a0l_, a1h_, a1l_, hacc);                                       \
  } while (0)

#define Z_EPI(ZACC, BIASP)                                                       \
  do {                                                                           \
    _Pragma("unroll")                                                            \
    for (int ct_ = 0; ct_ < 8; ++ct_) {                                          \
      int col_ = ct_ * 16 + li;                                                  \
      float bv_ = (BIASP)[col_];                                                 \
      _Pragma("unroll")                                                          \
      for (int sub_ = 0; sub_ < 2; ++sub_) {                                     \
        _Pragma("unroll")                                                        \
        for (int r_ = 0; r_ < 4; ++r_) {                                         \
          float v_ = (ZACC)[sub_][ct_][r_] + bv_;                                \
          v_ = v_ >= 0.f ? v_ : 0.01f * v_;                                      \
          int row_ = w * 32 + sub_ * 16 + lg * 4 + r_;                           \
          int byte_ = row_ * 256 + col_ * 2;                                     \
          byte_ ^= (row_ & 7) << 4;                                              \
          unsigned int u_ = __float_as_uint(v_);                                 \
          *(unsigned short*)((char*)z_hi + byte_) = (unsigned short)(u_ >> 16);  \
          float lo_ = v_ - __uint_as_float(u_ & 0xFFFF0000u);                    \
          *(unsigned short*)((char*)z_lo + byte_) = (unsigned short)(__float_as_uint(lo_) >> 16); \
        }                                                                        \
      }                                                                          \
    }                                                                            \
  } while (0)

#define PHASE_B(SLICE)                                                           \
  do {                                                                           \
    const unsigned short* qh0_ = Wt + OFF_WIN_HI + cr0 * 512 + (SLICE) * 128 + c0 * 8; \
    const unsigned short* ql0_ = Wt + OFF_WIN_LO + cr0 * 512 + (SLICE) * 128 + c0 * 8; \
    const unsigned short* qh1_ = Wt + OFF_WIN_HI + cr1 * 512 + (SLICE) * 128 + c0 * 8; \
    const unsigned short* ql1_ = Wt + OFF_WIN_LO + cr1 * 512 + (SLICE) * 128 + c0 * 8; \
    uint4 wA0_ = *(const uint4*)(qh0_), wA1_ = *(const uint4*)(ql0_);            \
    uint4 wA2_ = *(const uint4*)(qh1_), wA3_ = *(const uint4*)(ql1_);            \
    uint4 wB0_, wB1_, wB2_, wB3_;                                                \
    STORE_BT(wA0_, wA1_, wA2_, wA3_);                                            \
    lgkm0_barrier();                                                             \
    wB0_ = *(const uint4*)(qh0_ + 32); wB1_ = *(const uint4*)(ql0_ + 32);        \
    wB2_ = *(const uint4*)(qh1_ + 32); wB3_ = *(const uint4*)(ql1_ + 32);        \
    MFMA_B(0);                                                                   \
    fence_barrier();                                                             \
    STORE_BT(wB0_, wB1_, wB2_, wB3_);                                            \
    lgkm0_barrier();                                                             \
    wA0_ = *(const uint4*)(qh0_ + 64); wA1_ = *(const uint4*)(ql0_ + 64);        \
    wA2_ = *(const uint4*)(qh1_ + 64); wA3_ = *(const uint4*)(ql1_ + 64);        \
    MFMA_B(1);                                                                   \
    fence_barrier();                                                             \
    STORE_BT(wA0_, wA1_, wA2_, wA3_);                                            \
    lgkm0_barrier();                                                             \
    wB0_ = *(const uint4*)(qh0_ + 96); wB1_ = *(const uint4*)(ql0_ + 96);        \
    wB2_ = *(const uint4*)(qh1_ + 96); wB3_ = *(const uint4*)(ql1_ + 96);        \
    MFMA_B(2);                                                                   \
    fence_barrier();                                                             \
    STORE_BT(wB0_, wB1_, wB2_, wB3_);                                            \
    lgkm0_barrier();                                                             \
    MFMA_B(3);                                                                   \
    fence_barrier();                                                             \
  } while (0)

  f32x4 hacc[2][8];
#pragma unroll
  for (int a = 0; a < 2; ++a)
#pragma unroll
    for (int b = 0; b < 8; ++b) hacc[a][b] = (f32x4)0.f;

  // ---- big segments: des (s=0), tweet (s=1); K=768 = 24 K-tiles, pipelined ----
#pragma unroll
  for (int s = 0; s < 2; ++s) {
    const int off = (s == 0) ? 785 : 6;
    const unsigned short* wh = Wt + (s == 0 ? OFF_DES_HI : OFF_TW_HI);
    const unsigned short* wl = Wt + (s == 0 ? OFF_DES_LO : OFF_TW_LO);
    const float* bias = (s == 0) ? bdes : btw;

    const float* xr0 = xrow0 + off + lg * 8;
    const float* xr1 = xrow1 + off + lg * 8;
    const unsigned short* ph0 = wh + cr0 * 768 + c0 * 8;
    const unsigned short* pl0 = wl + cr0 * 768 + c0 * 8;
    const unsigned short* ph1 = wh + cr1 * 768 + c0 * 8;
    const unsigned short* pl1 = wl + cr1 * 768 + c0 * 8;

    f32x4 zacc[2][8];
#pragma unroll
    for (int a = 0; a < 2; ++a)
#pragma unroll
      for (int b = 0; b < 8; ++b) zacc[a][b] = (f32x4)0.f;

    uint4 WA0, WA1, WA2, WA3, WB0, WB1, WB2, WB3;
    f32x4u X0a0, X0b0, X0a1, X0b1, X1a0, X1b0, X1a1, X1b1;

    // prologue: W tile 0, X tiles 0..1 (depth-2 ping-pong)
    WA0 = *(const uint4*)(ph0); WA1 = *(const uint4*)(pl0);
    WA2 = *(const uint4*)(ph1); WA3 = *(const uint4*)(pl1);
    X0a0 = *(const f32x4u*)(xr0);      X0b0 = *(const f32x4u*)(xr0 + 4);
    X0a1 = *(const f32x4u*)(xr1);      X0b1 = *(const f32x4u*)(xr1 + 4);
    X1a0 = *(const f32x4u*)(xr0 + 32); X1b0 = *(const f32x4u*)(xr0 + 36);
    X1a1 = *(const f32x4u*)(xr1 + 32); X1b1 = *(const f32x4u*)(xr1 + 36);

    for (int base = 0; base < 24; base += 2) {
      TILE(WA0, WA1, WA2, WA3, WB0, WB1, WB2, WB3, X0a0, X0b0, X0a1, X0b1, base + 0);
      TILE(WB0, WB1, WB2, WB3, WA0, WA1, WA2, WA3, X1a0, X1b0, X1a1, X1b1, base + 1);
    }
    Z_EPI(zacc, bias);   // z slots are wave-private
    PHASE_B(s);
  }

  // ---- small segments: num (K=6), cat (K=11); single padded K-tile each ----
#pragma unroll
  for (int u = 0; u < 2; ++u) {
    const int offu = (u == 0) ? 0 : 774;
    const int Ksu = (u == 0) ? 6 : 11;
    const unsigned short* wh = Wt + (u == 0 ? OFF_NUM_HI : OFF_CAT_HI);
    const unsigned short* wl = Wt + (u == 0 ? OFF_NUM_LO : OFF_CAT_LO);
    const float* biasu = (u == 0) ? bnum : bcat;
    const float* xr0 = xrow0 + offu + lg * 8;
    const float* xr1 = xrow1 + offu + lg * 8;

    uint4 s0 = *(const uint4*)(wh + cr0 * 32 + c0 * 8);
    uint4 s1 = *(const uint4*)(wl + cr0 * 32 + c0 * 8);
    uint4 s2 = *(const uint4*)(wh + cr1 * 32 + c0 * 8);
    uint4 s3 = *(const uint4*)(wl + cr1 * 32 + c0 * 8);
    f32x4u fa0 = *(const f32x4u*)(xr0);
    f32x4u fb0 = *(const f32x4u*)(xr0 + 4);
    f32x4u fa1 = *(const f32x4u*)(xr1);
    f32x4u fb1 = *(const f32x4u*)(xr1 + 4);
#pragma unroll
    for (int j = 0; j < 4; ++j) {
      if (lg * 8 + j >= Ksu) { fa0[j] = 0.f; fa1[j] = 0.f; }
      if (lg * 8 + 4 + j >= Ksu) { fb0[j] = 0.f; fb1[j] = 0.f; }
    }

    f32x4 zacc[2][8];
#pragma unroll
    for (int a = 0; a < 2; ++a)
#pragma unroll
      for (int b = 0; b < 8; ++b) zacc[a][b] = (f32x4)0.f;

    STORE_BT(s0, s1, s2, s3);
    lgkm0_barrier();
    {
      Frag a0h_, a0l_, a1h_, a1l_;
      CVT_A2(fa0, fb0, a0h_, a0l_);
      CVT_A2(fa1, fb1, a1h_, a1l_);
      MFMA8_2(a0h_, a0l_, a1h_, a1l_, zacc);
    }
    fence_barrier();
    Z_EPI(zacc, biasu);
    PHASE_B(u + 2);
  }

  // epilogue: + b_in, PReLU, store (f32 + RNE-bf16 copy for the gather)
#pragma unroll
  for (int ct = 0; ct < 8; ++ct) {
    int col = ct * 16 + li;
    float bi = bin[col];
    float p = pa[col];
#pragma unroll
    for (int sub = 0; sub < 2; ++sub) {
#pragma unroll
      for (int r = 0; r < 4; ++r) {
        int node = node0 + w * 32 + sub * 16 + lg * 4 + r;
        if (node < NN) {
          float v = hacc[sub][ct][r] + bi;
          v = v >= 0.f ? v : p * v;
          h0[(size_t)node * HD + col] = v;
          h16[(size_t)node * HD + col] = bf16_rne(v);
        }
      }
    }
  }

#undef TILE
#undef MFMA_B
#undef Z_EPI
#undef PHASE_B
#undef MFMA8_2
#undef CVT_A2
#undef STORE_BT
}

// ---------------- neighbor-mean gather (bf16 in, bf16 out) ----------------------
__global__ __launch_bounds__(256) void k_gather(
    const unsigned short* __restrict__ h16, unsigned short* __restrict__ agg16,
    const int* __restrict__ row_ptr, const int* __restrict__ cnt2,
    const int* __restrict__ entries) {
  int i = blockIdx.x * 4 + (threadIdx.x >> 6);
  int l = threadIdx.x & 63;
  if (i >= NN) return;
  int rs = row_ptr[i], re = row_ptr[i + 1];
  int c0 = cnt2[i], c1 = cnt2[NN + i];
  float inv0 = 1.f / (float)(c0 > 0 ? c0 : 1);
  float inv1 = 1.f / (float)(c1 > 0 ? c1 : 1);
  float a0 = 0, a1 = 0, b0 = 0, b1 = 0;
  int e = rs;
  for (; e + 3 < re; e += 4) {
    int ent0 = entries[e], ent1 = entries[e + 1];
    int ent2 = entries[e + 2], ent3 = entries[e + 3];
    unsigned int p0 = ((const unsigned int*)(h16 + (size_t)(ent0 & 0xFFFFF) * HD))[l];
    unsigned int p1 = ((const unsigned int*)(h16 + (size_t)(ent1 & 0xFFFFF) * HD))[l];
    unsigned int p2 = ((const unsigned int*)(h16 + (size_t)(ent2 & 0xFFFFF) * HD))[l];
    unsigned int p3 = ((const unsigned int*)(h16 + (size_t)(ent3 & 0xFFFFF) * HD))[l];
    float v0x = __uint_as_float(p0 << 16), v0y = __uint_as_float(p0 & 0xFFFF0000u);
    float v1x = __uint_as_float(p1 << 16), v1y = __uint_as_float(p1 & 0xFFFF0000u);
    float v2x = __uint_as_float(p2 << 16), v2y = __uint_as_float(p2 & 0xFFFF0000u);
    float v3x = __uint_as_float(p3 << 16), v3y = __uint_as_float(p3 & 0xFFFF0000u);
    if (ent0 >> 20) { b0 += v0x; b1 += v0y; } else { a0 += v0x; a1 += v0y; }
    if (ent1 >> 20) { b0 += v1x; b1 += v1y; } else { a0 += v1x; a1 += v1y; }
    if (ent2 >> 20) { b0 += v2x; b1 += v2y; } else { a0 += v2x; a1 += v2y; }
    if (ent3 >> 20) { b0 += v3x; b1 += v3y; } else { a0 += v3x; a1 += v3y; }
  }
  for (; e < re; ++e) {
    int ent = entries[e];
    unsigned int p0 = ((const unsigned int*)(h16 + (size_t)(ent & 0xFFFFF) * HD))[l];
    float v0x = __uint_as_float(p0 << 16), v0y = __uint_as_float(p0 & 0xFFFF0000u);
    if (ent >> 20) { b0 += v0x; b1 += v0y; } else { a0 += v0x; a1 += v0y; }
  }
  // pack: even col (2l) low half, odd col (2l+1) high half — matches cvt_pair order
  unsigned int* q0 = (unsigned int*)(agg16 + (size_t)i * HD);
  unsigned int* q1 = (unsigned int*)(agg16 + (size_t)NN * HD + (size_t)i * HD);
  q0[l] = (unsigned int)bf16_rne(a0 * inv0) | ((unsigned int)bf16_rne(a1 * inv0) << 16);
  q1[l] = (unsigned int)bf16_rne(b0 * inv1) | ((unsigned int)bf16_rne(b1 * inv1) << 16);
}

// ---------------- fused layer GEMM: out = [h|agg0|agg1] @ [root;rel0;rel1] + b ---
// kt 0-3: hin (f32, split-bf16, 3 MFMAs/tile). kt 4-11: agg16 (bf16 A-operand,
// A_lo = 0 exactly => al*bh MFMA dropped: 2 MFMAs/tile, bit-identical).
__global__ __launch_bounds__(256, 4) void k_rgemm2(
    const float* __restrict__ hin, const unsigned short* __restrict__ agg16,
    const unsigned short* __restrict__ wl_hi, const unsigned short* __restrict__ wl_lo,
    const float* __restrict__ bias, float* __restrict__ outp,
    unsigned short* __restrict__ h16out) {
  __shared__ unsigned short bt_hi[128 * 32], bt_lo[128 * 32];   // 8KB + 8KB

  const int t = threadIdx.x;
  const int node0 = blockIdx.x * 64;
  const int w = t >> 6, lane = t & 63;
  const int li = lane & 15, lg = lane >> 4;

  const int cr0 = t >> 2, c0 = t & 3;
  const int cr1 = cr0 + 64;
  const unsigned stb0 = cr0 * 64 + ((c0 ^ ((cr0 >> 1) & 3)) << 4);
  const unsigned stb1 = cr1 * 64 + ((c0 ^ ((cr1 >> 1) & 3)) << 4);

  const int rowA = w * 16 + li;
  int nodeA = node0 + rowA;
  int ndA = nodeA < NN ? nodeA : NN - 1;
  const float* a0p = hin + (size_t)ndA * HD + lg * 8;
  const unsigned short* g0p = agg16 + (size_t)ndA * HD + lg * 8;
  const unsigned short* g1p = agg16 + (size_t)NN * HD + (size_t)ndA * HD + lg * 8;

#define STORE_BT(SH0, SL0, SH1, SL1)              \
  do {                                            \
    *(uint4*)((char*)bt_hi + stb0) = (SH0);       \
    *(uint4*)((char*)bt_lo + stb0) = (SL0);       \
    *(uint4*)((char*)bt_hi + stb1) = (SH1);       \
    *(uint4*)((char*)bt_lo + stb1) = (SL1);       \
  } while (0)

#define CVT_A2(FA, FB, AH, AL)                                                   \
  do {                                                                           \
    cvt_pair((FA)[0], (FA)[1], (AH).u[0], (AL).u[0]);                            \
    cvt_pair((FA)[2], (FA)[3], (AH).u[1], (AL).u[1]);                            \
    cvt_pair((FB)[0], (FB)[1], (AH).u[2], (AL).u[2]);                            \
    cvt_pair((FB)[2], (FB)[3], (AH).u[3], (AL).u[3]);                            \
  } while (0)

// split path: 3 MFMAs per col-tile
#define MFMA8F(AH, AL)                                                           \
  do {                                                                           \
    _Pragma("unroll")                                                            \
    for (int ct_ = 0; ct_ < 8; ++ct_) {                                          \
      int colrow_ = ct_ * 16 + li;                                               \
      int byte_ = colrow_ * 64 + (lg << 4);                                      \
      byte_ ^= ((colrow_ >> 1) & 3) << 4;                                        \
      Frag bh_, bl_;                                                             \
      bh_.v = *(const uint4*)((char*)bt_hi + byte_);                             \
      bl_.v = *(const uint4*)((char*)bt_lo + byte_);                             \
      acc[ct_] = __builtin_amdgcn_mfma_f32_16x16x32_bf16((AH).s, bl_.s, acc[ct_], 0, 0, 0); \
      acc[ct_] = __builtin_amdgcn_mfma_f32_16x16x32_bf16((AL).s, bh_.s, acc[ct_], 0, 0, 0); \
      acc[ct_] = __builtin_amdgcn_mfma_f32_16x16x32_bf16((AH).s, bh_.s, acc[ct_], 0, 0, 0); \
    }                                                                            \
  } while (0)

// bf16-A path: A_lo == 0 exactly -> 2 MFMAs per col-tile (bit-identical)
#define MFMA8H(AH)                                                               \
  do {                                                                           \
    _Pragma("unroll")                                                            \
    for (int ct_ = 0; ct_ < 8; ++ct_) {                                          \
      int colrow_ = ct_ * 16 + li;                                               \
      int byte_ = colrow_ * 64 + (lg << 4);                                      \
      byte_ ^= ((colrow_ >> 1) & 3) << 4;                                        \
      Frag bh_, bl_;                                                             \
      bh_.v = *(const uint4*)((char*)bt_hi + byte_);                             \
      bl_.v = *(const uint4*)((char*)bt_lo + byte_);                             \
      acc[ct_] = __builtin_amdgcn_mfma_f32_16x16x32_bf16((AH).s, bl_.s, acc[ct_], 0, 0, 0); \
      acc[ct_] = __builtin_amdgcn_mfma_f32_16x16x32_bf16((AH).s, bh_.s, acc[ct_], 0, 0, 0); \
    }                                                                            \
  } while (0)

#define W2H(KT, CR) (wl_hi + ((KT) >> 2) * 16384 + (CR) * 128 + ((KT) & 3) * 32 + c0 * 8)
#define W2L(KT, CR) (wl_lo + ((KT) >> 2) * 16384 + (CR) * 128 + ((KT) & 3) * 32 + c0 * 8)
// bf16 agg A source for local tile j (0..7): rel0 j 0..3, rel1 j 4..7
#define GSRC(J) ((J) < 4 ? (g0p + (J) * 32) : (g1p + ((J) - 4) * 32))

  f32x4 acc[8];
#pragma unroll
  for (int b = 0; b < 8; ++b) acc[b] = (f32x4)0.f;

  uint4 WA0, WA1, WA2, WA3, WB0, WB1, WB2, WB3;
  f32x4u X0a, X0b, X1a, X1b, X2a, X2b;
  uint4 Y0, Y1;

  // prologue: W tile 0, hin tiles 0..2
  WA0 = *(const uint4*)W2H(0, cr0); WA1 = *(const uint4*)W2L(0, cr0);
  WA2 = *(const uint4*)W2H(0, cr1); WA3 = *(const uint4*)W2L(0, cr1);
  X0a = *(const f32x4u*)(a0p);      X0b = *(const f32x4u*)(a0p + 4);
  X1a = *(const f32x4u*)(a0p + 32); X1b = *(const f32x4u*)(a0p + 36);
  X2a = *(const f32x4u*)(a0p + 64); X2b = *(const f32x4u*)(a0p + 68);

  // ---- f32 section: kt 0..3 ----
  STORE_BT(WA0, WA1, WA2, WA3);
  lgkm0_barrier();
  {
    Frag ah_, al_;
    CVT_A2(X0a, X0b, ah_, al_);
    WB0 = *(const uint4*)W2H(1, cr0); WB1 = *(const uint4*)W2L(1, cr0);
    WB2 = *(const uint4*)W2H(1, cr1); WB3 = *(const uint4*)W2L(1, cr1);
    X0a = *(const f32x4u*)(a0p + 96); X0b = *(const f32x4u*)(a0p + 100);
    MFMA8F(ah_, al_);
  }
  fence_barrier();
  STORE_BT(WB0, WB1, WB2, WB3);
  lgkm0_barrier();
  {
    Frag ah_, al_;
    CVT_A2(X1a, X1b, ah_, al_);
    WA0 = *(const uint4*)W2H(2, cr0); WA1 = *(const uint4*)W2L(2, cr0);
    WA2 = *(const uint4*)W2H(2, cr1); WA3 = *(const uint4*)W2L(2, cr1);
    Y0 = *(const uint4*)GSRC(0);
    MFMA8F(ah_, al_);
  }
  fence_barrier();
  STORE_BT(WA0, WA1, WA2, WA3);
  lgkm0_barrier();
  {
    Frag ah_, al_;
    CVT_A2(X2a, X2b, ah_, al_);
    WB0 = *(const uint4*)W2H(3, cr0); WB1 = *(const uint4*)W2L(3, cr0);
    WB2 = *(const uint4*)W2H(3, cr1); WB3 = *(const uint4*)W2L(3, cr1);
    Y1 = *(const uint4*)GSRC(1);
    MFMA8F(ah_, al_);
  }
  fence_barrier();
  STORE_BT(WB0, WB1, WB2, WB3);
  lgkm0_barrier();
  {
    Frag ah_, al_;
    CVT_A2(X0a, X0b, ah_, al_);
    WA0 = *(const uint4*)W2H(4, cr0); WA1 = *(const uint4*)W2L(4, cr0);
    WA2 = *(const uint4*)W2H(4, cr1); WA3 = *(const uint4*)W2L(4, cr1);
    MFMA8F(ah_, al_);
  }
  fence_barrier();

  // ---- bf16 agg section: local tiles 0..7 (kt 4..11), Y ping-pong depth-2 ----
#define TILEB(WC0, WC1, WC2, WC3, WN0, WN1, WN2, WN3, YB, J)                     \
  do {                                                                           \
    STORE_BT(WC0, WC1, WC2, WC3);                                                \
    lgkm0_barrier();                                                             \
    Frag ah_;                                                                    \
    ah_.v = (YB);                                                                \
    {                                                                            \
      int kn_ = (J) + 5; if (kn_ > 11) kn_ = 11;                                 \
      WN0 = *(const uint4*)W2H(kn_, cr0); WN1 = *(const uint4*)W2L(kn_, cr0);    \
      WN2 = *(const uint4*)W2H(kn_, cr1); WN3 = *(const uint4*)W2L(kn_, cr1);    \
      int jy_ = (J) + 2; if (jy_ > 7) jy_ = 7;                                   \
      (YB) = *(const uint4*)GSRC(jy_);                                           \
    }                                                                            \
    MFMA8H(ah_);                                                                 \
    fence_barrier();                                                             \
  } while (0)

  TILEB(WA0, WA1, WA2, WA3, WB0, WB1, WB2, WB3, Y0, 0);
  TILEB(WB0, WB1, WB2, WB3, WA0, WA1, WA2, WA3, Y1, 1);
  TILEB(WA0, WA1, WA2, WA3, WB0, WB1, WB2, WB3, Y0, 2);
  TILEB(WB0, WB1, WB2, WB3, WA0, WA1, WA2, WA3, Y1, 3);
  TILEB(WA0, WA1, WA2, WA3, WB0, WB1, WB2, WB3, Y0, 4);
  TILEB(WB0, WB1, WB2, WB3, WA0, WA1, WA2, WA3, Y1, 5);
  TILEB(WA0, WA1, WA2, WA3, WB0, WB1, WB2, WB3, Y0, 6);
  TILEB(WB0, WB1, WB2, WB3, WA0, WA1, WA2, WA3, Y1, 7);

  // epilogue: + bias, store (and optional bf16 copy)
#pragma unroll
  for (int ct = 0; ct < 8; ++ct) {
    int col = ct * 16 + li;
    float bv = bias[col];
#pragma unroll
    for (int r = 0; r < 4; ++r) {
      int node = node0 + w * 16 + lg * 4 + r;
      if (node < NN) {
        float v = acc[ct][r] + bv;
        outp[(size_t)node * HD + col] = v;
        if (h16out) h16out[(size_t)node * HD + col] = bf16_rne(v);
      }
    }
  }

#undef TILEB
#undef GSRC
#undef W2H
#undef W2L
#undef MFMA8H
#undef MFMA8F
#undef CVT_A2
#undef STORE_BT
}

extern "C" void kernel_launch(void* const* d_in, const int* in_sizes, int n_in,
                              void* d_out, int out_size, void* d_ws, size_t ws_size,
                              hipStream_t stream) {
  const float* x    = (const float*)d_in[0];
  const int* ei     = (const int*)d_in[1];
  const int* et     = (const int*)d_in[2];
  const float* Wdes = (const float*)d_in[3];
  const float* bdes = (const float*)d_in[4];
  const float* Wtw  = (const float*)d_in[5];
  const float* btw  = (const float*)d_in[6];
  const float* Wnum = (const float*)d_in[7];
  const float* bnum = (const float*)d_in[8];
  const float* Wcat = (const float*)d_in[9];
  const float* bcat = (const float*)d_in[10];
  const float* Win  = (const float*)d_in[11];
  const float* bin  = (const float*)d_in[12];
  const float* pa   = (const float*)d_in[13];
  const float* root1 = (const float*)d_in[14];
  const float* rel1  = (const float*)d_in[15];
  const float* bias1 = (const float*)d_in[16];
  const float* root2 = (const float*)d_in[17];
  const float* rel2  = (const float*)d_in[18];
  const float* bias2 = (const float*)d_in[19];
  const float* Wcls  = (const float*)d_in[20];
  const float* bcls  = (const float*)d_in[21];
  float* out = (float*)d_out;

  char* p = (char*)d_ws;
  unsigned short* agg16 = (unsigned short*)p; p += (size_t)2 * NN * HD * 2;  // 51.2 MB
  float* hB = (float*)p;      p += (size_t)NN * HD * 4;       // 51.2 MB
  int* row_ptr = (int*)p;     p += ((size_t)NN + 4) * 4;
  int* cnt2 = (int*)p;        p += (size_t)2 * NN * 4;
  int* fillpos = (int*)p;     p += (size_t)NN * 4;
  int* entries = (int*)p;     p += (size_t)EE * 4;
  int* bsum = (int*)p;        p += 512;
  float* bfused = (float*)p;  p += 512;
  unsigned short* h16 = (unsigned short*)p; p += (size_t)NN * HD * 2;  // 25.6 MB
  unsigned short* Wt = (unsigned short*)p;  p += (size_t)WT_SITES * 2 * 2;

  // zero counters first (cnt2 + fillpos)
  (void)hipMemsetAsync(cnt2, 0, (size_t)3 * NN * 4, stream);
  // setup: weight pre-convert + edge count + classifier fusion, one launch
  k_setup<<<PREPW_BLOCKS + COUNT_BLOCKS + FUSEW_BLOCKS, 256, 0, stream>>>(
      Wdes, Wtw, Wnum, Wcat, Win, root1, rel1, root2, rel2, Wcls, Wt,
      ei, et, cnt2, bias2, bcls, bfused);

  // CSR scans
  int nb = (NN + 1023) / 1024;
  k_scan1<<<nb, 256, 0, stream>>>(cnt2, row_ptr, bsum);
  k_scan2<<<1, 128, 0, stream>>>(bsum, nb);
  k_scan3<<<(NN + 1 + 255) / 256, 256, 0, stream>>>(row_ptr, bsum);

  // h0 -> d_out (+ h16 bf16 copy), with CSR fill fused in (blocks >= PROJ128_NBLK)
  k_proj2<<<PROJ128_NBLK + FILL_BLOCKS, 256, 0, stream>>>(
      x, bdes, btw, bnum, bcat, bin, pa, Wt, out, h16,
      ei, et, row_ptr, fillpos, entries);
  // layer 1: gather neighbor means (bf16 in/out), then fused K=384 GEMM -> hB
  k_gather<<<NN / 4, 256, 0, stream>>>(h16, agg16, row_ptr, cnt2, entries);
  k_rgemm2<<<NBLK64, 256, 0, stream>>>(out, agg16, Wt + OFF_L1_HI, Wt + OFF_L1_LO,
                                       bias1, hB, h16);
  // layer 2 + classifier (algebraically fused): out = [hB|agg] @ (W2@Wcls) + bfused
  k_gather<<<NN / 4, 256, 0, stream>>>(h16, agg16, row_ptr, cnt2, entries);
  k_rgemm2<<<NBLK64, 256, 0, stream>>>(hB, agg16, Wt + OFF_L2_HI, Wt + OFF_L2_LO,
                                       bfused, out, (unsigned short*)nullptr);
}

// Round 16
// 803.849 us; speedup vs baseline: 1.0344x; 1.0344x over previous
//
#include <hip/hip_runtime.h>
#include <cstdint>
#include <cstddef>

#define NN 100000
#define EE 1600000
#define XDIM 1553
#define HD 128

typedef __attribute__((ext_vector_type(8))) short short8;
typedef __attribute__((ext_vector_type(4))) float f32x4;
// unaligned-capable 4-float vector: hardware allows 4B-aligned dwordx4
typedef float f32x4u __attribute__((vector_size(16), aligned(4)));

union Frag { unsigned int u[4]; short8 s; uint4 v; };

// weight area offsets (ushort units); hi/lo are separate regions
#define OFF_DES_HI 0
#define OFF_DES_LO 98304
#define OFF_TW_HI  196608
#define OFF_TW_LO  294912
#define OFF_NUM_HI 393216
#define OFF_NUM_LO 397312
#define OFF_CAT_HI 401408
#define OFF_CAT_LO 405504
#define OFF_WIN_HI 409600
#define OFF_WIN_LO 475136
#define OFF_L1_HI  540672
#define OFF_L1_LO  589824
#define OFF_L2_HI  638976
#define OFF_L2_LO  688128
#define WT_SITES   385024   // (col,k) region size (L2/CLS write-sites skipped)

#define PREPW_BLOCKS 1504
#define COUNT_BLOCKS 6250   // EE / 256
#define FUSEW_BLOCKS 193    // 2 fused-k rows per block (k = 0..385)
#define NBLK64       1563   // (NN + 63) / 64   (rgemm2 grid)
#define PROJ128_NBLK 782    // (NN + 127) / 128 (proj grid)
#define FILL_BLOCKS  6250   // EE / 256

// hi = trunc-bf16(f), lo = trunc-bf16(f - hi). Packed: 2 elems -> 1 u32 via v_perm.
__device__ __forceinline__ void cvt_pair(float f0, float f1,
                                         unsigned int& hi, unsigned int& lo) {
  unsigned int u0 = __float_as_uint(f0), u1 = __float_as_uint(f1);
  hi = __builtin_amdgcn_perm(u1, u0, 0x07060302u);
  float l0 = f0 - __uint_as_float(u0 & 0xFFFF0000u);
  float l1 = f1 - __uint_as_float(u1 & 0xFFFF0000u);
  lo = __builtin_amdgcn_perm(__float_as_uint(l1), __float_as_uint(l0), 0x07060302u);
}

// round-to-nearest-even bf16
__device__ __forceinline__ unsigned short bf16_rne(float f) {
  unsigned int u = __float_as_uint(f);
  return (unsigned short)((u + 0x7FFFu + ((u >> 16) & 1u)) >> 16);
}

// raw barriers: no vmcnt drain (prefetched global loads ride across);
// lgkm0 variant publishes ds_writes before the barrier.
__device__ __forceinline__ void fence_barrier() {
  asm volatile("" ::: "memory");
  __builtin_amdgcn_s_barrier();
  asm volatile("" ::: "memory");
}
__device__ __forceinline__ void lgkm0_barrier() {
  asm volatile("s_waitcnt lgkmcnt(0)" ::: "memory");
  __builtin_amdgcn_s_barrier();
  asm volatile("" ::: "memory");
}

// ---------------- setup: weight pre-convert + edge count + classifier fusion ----
// blocks [0, PREPW): transpose/split weights (L2/CLS ranges dead: fusew owns L2).
// blocks [PREPW, +COUNT): edge count atomics. blocks [+COUNT, +FUSEW): Wfused =
// [root2;rel2]@Wcls into OFF_L2 (reads original inputs only -> no race). One launch.
__global__ __launch_bounds__(256) void k_setup(
    const float* __restrict__ Wdes, const float* __restrict__ Wtw,
    const float* __restrict__ Wnum, const float* __restrict__ Wcat,
    const float* __restrict__ Win,  const float* __restrict__ root1,
    const float* __restrict__ rel1, const float* __restrict__ root2,
    const float* __restrict__ rel2, const float* __restrict__ Wcls,
    unsigned short* __restrict__ Wt,
    const int* __restrict__ ei, const int* __restrict__ et,
    int* __restrict__ cnt2,
    const float* __restrict__ bias2, const float* __restrict__ bcls,
    float* __restrict__ bfused) {
  if (blockIdx.x >= PREPW_BLOCKS + COUNT_BLOCKS) {
    // classifier fusion
    int fb = blockIdx.x - (PREPW_BLOCKS + COUNT_BLOCKS);
    int k = fb * 2 + (threadIdx.x >> 7);
    int c = threadIdx.x & 127;
    if (k > 384) return;
    const float* wrow;
    if (k < 128)      wrow = root2 + (size_t)k * 128;
    else if (k < 256) wrow = rel2 + (size_t)(k - 128) * 128;
    else if (k < 384) wrow = rel2 + 16384 + (size_t)(k - 256) * 128;
    else              wrow = bias2;
    float s = 0.f;
    for (int j = 0; j < 128; ++j) s += wrow[j] * Wcls[(size_t)j * 128 + c];
    if (k == 384) { bfused[c] = s + bcls[c]; return; }
    unsigned int u = __float_as_uint(s);
    float lo = s - __uint_as_float(u & 0xFFFF0000u);
    int sub = k >> 7, kl = k & 127;
    Wt[OFF_L2_HI + sub * 16384 + c * 128 + kl] = (unsigned short)(u >> 16);
    Wt[OFF_L2_LO + sub * 16384 + c * 128 + kl] = (unsigned short)(__float_as_uint(lo) >> 16);
    return;
  }
  if (blockIdx.x >= PREPW_BLOCKS) {
    int e = (blockIdx.x - PREPW_BLOCKS) * 256 + threadIdx.x;
    if (e < EE) atomicAdd(&cnt2[et[e] * NN + ei[EE + e]], 1);
    return;
  }
  int id = blockIdx.x * 256 + threadIdx.x;
  if (id >= 319488) return;   // root2/rel2/Wcls sites dead (fusew owns OFF_L2)
  const float* src; int K, Kpad, dhi, dlo, local;
  if (id < 98304)       { src=Wdes;        K=768; Kpad=768; dhi=OFF_DES_HI;       dlo=OFF_DES_LO;       local=id; }
  else if (id < 196608) { src=Wtw;         K=768; Kpad=768; dhi=OFF_TW_HI;        dlo=OFF_TW_LO;        local=id-98304; }
  else if (id < 200704) { src=Wnum;        K=6;   Kpad=32;  dhi=OFF_NUM_HI;       dlo=OFF_NUM_LO;       local=id-196608; }
  else if (id < 204800) { src=Wcat;        K=11;  Kpad=32;  dhi=OFF_CAT_HI;       dlo=OFF_CAT_LO;       local=id-200704; }
  else if (id < 270336) { src=Win;         K=512; Kpad=512; dhi=OFF_WIN_HI;       dlo=OFF_WIN_LO;       local=id-204800; }
  else if (id < 286720) { src=root1;       K=128; Kpad=128; dhi=OFF_L1_HI;        dlo=OFF_L1_LO;        local=id-270336; }
  else if (id < 303104) { src=rel1;        K=128; Kpad=128; dhi=OFF_L1_HI+16384;  dlo=OFF_L1_LO+16384;  local=id-286720; }
  else                  { src=rel1+16384;  K=128; Kpad=128; dhi=OFF_L1_HI+32768;  dlo=OFF_L1_LO+32768;  local=id-303104; }
  int col = local / Kpad;
  int k = local - col * Kpad;
  float v = (k < K) ? src[(size_t)k * 128 + col] : 0.f;
  unsigned int u = __float_as_uint(v);
  float lo = v - __uint_as_float(u & 0xFFFF0000u);
  Wt[dhi + col * Kpad + k] = (unsigned short)(u >> 16);
  Wt[dlo + col * Kpad + k] = (unsigned short)(__float_as_uint(lo) >> 16);
}

// ---------------- CSR scans ----------------
__global__ __launch_bounds__(256) void k_scan1(const int* __restrict__ cnt2,
                                               int* __restrict__ row_ptr,
                                               int* __restrict__ bsum) {
  __shared__ int sums[256];
  int t = threadIdx.x;
  int base = blockIdx.x * 1024 + t * 4;
  int v[4]; int s = 0;
#pragma unroll
  for (int j = 0; j < 4; ++j) {
    int idx = base + j;
    v[j] = (idx < NN) ? (cnt2[idx] + cnt2[NN + idx]) : 0;
    s += v[j];
  }
  sums[t] = s;
  __syncthreads();
  for (int d = 1; d < 256; d <<= 1) {
    int val = (t >= d) ? sums[t - d] : 0;
    __syncthreads();
    sums[t] += val;
    __syncthreads();
  }
  int excl = sums[t] - s;
  if (t == 255) bsum[blockIdx.x] = sums[t];
  int run = excl;
#pragma unroll
  for (int j = 0; j < 4; ++j) {
    int idx = base + j;
    if (idx < NN) row_ptr[idx] = run;
    run += v[j];
  }
}

__global__ __launch_bounds__(128) void k_scan2(int* __restrict__ bsum, int nb) {
  __shared__ int s[128];
  int t = threadIdx.x;
  int v = (t < nb) ? bsum[t] : 0;
  s[t] = v;
  __syncthreads();
  for (int d = 1; d < 128; d <<= 1) {
    int val = (t >= d) ? s[t - d] : 0;
    __syncthreads();
    s[t] += val;
    __syncthreads();
  }
  if (t < nb) bsum[t] = s[t] - v;
}

__global__ __launch_bounds__(256) void k_scan3(int* __restrict__ row_ptr,
                                               const int* __restrict__ bsum) {
  int idx = blockIdx.x * 256 + threadIdx.x;
  if (idx < NN) row_ptr[idx] += bsum[idx >> 10];
  if (idx == NN) row_ptr[NN] = EE;
}

// ---------------- fused projection + CSR fill (MFMA, split-bf16, raw barriers) ---
// Blocks 0..781: 128 nodes/block, 4 waves, wave = 32 rows (2 subs) x 128 cols.
// Blocks >= 782: CSR fill. Epilogue emits h0 (f32) + h16 (bf16). (No setprio:
// R15 showed it costs ~6% here — barrier-locked waves, m190 regime.)
__global__ __launch_bounds__(256, 2) void k_proj2(
    const float* __restrict__ x,
    const float* __restrict__ bdes, const float* __restrict__ btw,
    const float* __restrict__ bnum, const float* __restrict__ bcat,
    const float* __restrict__ bin,  const float* __restrict__ pa,
    const unsigned short* __restrict__ Wt, float* __restrict__ h0,
    unsigned short* __restrict__ h16,
    const int* __restrict__ ei, const int* __restrict__ et,
    const int* __restrict__ row_ptr, int* __restrict__ fillpos,
    int* __restrict__ entries) {
  __shared__ unsigned short bt_hi[128 * 32], bt_lo[128 * 32];   // 8KB + 8KB
  __shared__ unsigned short z_hi[128 * 128], z_lo[128 * 128];   // 32KB + 32KB

  if (blockIdx.x >= PROJ128_NBLK) {
    int e = (blockIdx.x - PROJ128_NBLK) * 256 + threadIdx.x;
    if (e < EE) {
      int src = ei[e];
      int dst = ei[EE + e];
      int r = et[e];
      int pos = atomicAdd(&fillpos[dst], 1);
      entries[row_ptr[dst] + pos] = src | (r << 20);
    }
    return;
  }

  const int t = threadIdx.x;
  const int node0 = blockIdx.x * 128;
  const int w = t >> 6, lane = t & 63;
  const int li = lane & 15, lg = lane >> 4;

  // B-staging constants (loop-invariant per thread)
  const int cr0 = t >> 2, c0 = t & 3;
  const int cr1 = cr0 + 64;
  const unsigned stb0 = cr0 * 64 + ((c0 ^ ((cr0 >> 1) & 3)) << 4);
  const unsigned stb1 = cr1 * 64 + ((c0 ^ ((cr1 >> 1) & 3)) << 4);

  // two A-rows per (wave, li): sub0 = w*32+li, sub1 = +16
  const int rowA0 = w * 32 + li;
  const int rowA1 = rowA0 + 16;
  int nodeA0 = node0 + rowA0; int nd0 = nodeA0 < NN ? nodeA0 : NN - 1;
  int nodeA1 = node0 + rowA1; int nd1 = nodeA1 < NN ? nodeA1 : NN - 1;
  const float* xrow0 = x + (size_t)nd0 * XDIM;
  const float* xrow1 = x + (size_t)nd1 * XDIM;

#define STORE_BT(SH0, SL0, SH1, SL1)              \
  do {                                            \
    *(uint4*)((char*)bt_hi + stb0) = (SH0);       \
    *(uint4*)((char*)bt_lo + stb0) = (SL0);       \
    *(uint4*)((char*)bt_hi + stb1) = (SH1);       \
    *(uint4*)((char*)bt_lo + stb1) = (SL1);       \
  } while (0)

#define CVT_A2(FA, FB, AH, AL)                                                   \
  do {                                                                           \
    cvt_pair((FA)[0], (FA)[1], (AH).u[0], (AL).u[0]);                            \
    cvt_pair((FA)[2], (FA)[3], (AH).u[1], (AL).u[1]);                            \
    cvt_pair((FB)[0], (FB)[1], (AH).u[2], (AL).u[2]);                            \
    cvt_pair((FB)[2], (FB)[3], (AH).u[3], (AL).u[3]);                            \
  } while (0)

// 8 col-tiles; B frags read ONCE, used by both subs.
#define MFMA8_2(A0H, A0L, A1H, A1L, ACC)                                         \
  do {                                                                           \
    _Pragma("unroll")                                                            \
    for (int ct_ = 0; ct_ < 8; ++ct_) {                                          \
      int colrow_ = ct_ * 16 + li;                                               \
      int byte_ = colrow_ * 64 + (lg << 4);                                      \
      byte_ ^= ((colrow_ >> 1) & 3) << 4;                                        \
      Frag bh_, bl_;                                                             \
      bh_.v = *(const uint4*)((char*)bt_hi + byte_);                             \
      bl_.v = *(const uint4*)((char*)bt_lo + byte_);                             \
      (ACC)[0][ct_] = __builtin_amdgcn_mfma_f32_16x16x32_bf16((A0H).s, bl_.s, (ACC)[0][ct_], 0, 0, 0); \
      (ACC)[0][ct_] = __builtin_amdgcn_mfma_f32_16x16x32_bf16((A0L).s, bh_.s, (ACC)[0][ct_], 0, 0, 0); \
      (ACC)[0][ct_] = __builtin_amdgcn_mfma_f32_16x16x32_bf16((A0H).s, bh_.s, (ACC)[0][ct_], 0, 0, 0); \
      (ACC)[1][ct_] = __builtin_amdgcn_mfma_f32_16x16x32_bf16((A1H).s, bl_.s, (ACC)[1][ct_], 0, 0, 0); \
      (ACC)[1][ct_] = __builtin_amdgcn_mfma_f32_16x16x32_bf16((A1L).s, bh_.s, (ACC)[1][ct_], 0, 0, 0); \
      (ACC)[1][ct_] = __builtin_amdgcn_mfma_f32_16x16x32_bf16((A1H).s, bh_.s, (ACC)[1][ct_], 0, 0, 0); \
    }                                                                            \
  } while (0)

#define TILE(WC0, WC1, WC2, WC3, WN0, WN1, WN2, WN3, XA0, XB0, XA1, XB1, T)      \
  do {                                                                           \
    STORE_BT(WC0, WC1, WC2, WC3);                                                \
    lgkm0_barrier();                                                             \
    Frag a0h_, a0l_, a1h_, a1l_;                                                 \
    CVT_A2(XA0, XB0, a0h_, a0l_);                                                \
    CVT_A2(XA1, XB1, a1h_, a1l_);                                                \
    {                                                                            \
      const int kw_ = ((T) + 1) * 32;                                            \
      WN0 = *(const uint4*)(ph0 + kw_); WN1 = *(const uint4*)(pl0 + kw_);        \
      WN2 = *(const uint4*)(ph1 + kw_); WN3 = *(const uint4*)(pl1 + kw_);        \
      int kx_ = (T) + 2; if (kx_ > 23) kx_ = 23; kx_ *= 32;                      \
      XA0 = *(const f32x4u*)(xr0 + kx_);                                         \
      XB0 = *(const f32x4u*)(xr0 + kx_ + 4);                                     \
      XA1 = *(const f32x4u*)(xr1 + kx_);                                         \
      XB1 = *(const f32x4u*)(xr1 + kx_ + 4);                                     \
    }                                                                            \
    MFMA8_2(a0h_, a0l_, a1h_, a1l_, zacc);                                       \
    fence_barrier();                                                             \
  } while (0)

#define MFMA_B(KT)                                                               \
  do {                                                                           \
    Frag a0h_, a0l_, a1h_, a1l_;                                                 \
    {                                                                            \
      int byte0_ = rowA0 * 256 + (((KT) * 32 + lg * 8) << 1);                    \
      byte0_ ^= (rowA0 & 7) << 4;                                                \
      a0h_.v = *(const uint4*)((char*)z_hi + byte0_);                            \
      a0l_.v = *(const uint4*)((char*)z_lo + byte0_);                            \
      int byte1_ = rowA1 * 256 + (((KT) * 32 + lg * 8) << 1);                    \
      byte1_ ^= (rowA1 & 7) << 4;                                                \
      a1h_.v = *(const uint4*)((char*)z_hi + byte1_);                            \
      a1l_.v = *(const uint4*)((char*)z_lo + byte1_);                            \
    }                                                                            \
    MFMA8_2(a0h_, a0l_, a1h_, a1l_, hacc);                                       \
  } while (0)

#define Z_EPI(ZACC, BIASP)                                                       \
  do {                                                                           \
    _Pragma("unroll")                                                            \
    for (int ct_ = 0; ct_ < 8; ++ct_) {                                          \
      int col_ = ct_ * 16 + li;                                                  \
      float bv_ = (BIASP)[col_];                                                 \
      _Pragma("unroll")                                                          \
      for (int sub_ = 0; sub_ < 2; ++sub_) {                                     \
        _Pragma("unroll")                                                        \
        for (int r_ = 0; r_ < 4; ++r_) {                                         \
          float v_ = (ZACC)[sub_][ct_][r_] + bv_;                                \
          v_ = v_ >= 0.f ? v_ : 0.01f * v_;                                      \
          int row_ = w * 32 + sub_ * 16 + lg * 4 + r_;                           \
          int byte_ = row_ * 256 + col_ * 2;                                     \
          byte_ ^= (row_ & 7) << 4;                                              \
          unsigned int u_ = __float_as_uint(v_);                                 \
          *(unsigned short*)((char*)z_hi + byte_) = (unsigned short)(u_ >> 16);  \
          float lo_ = v_ - __uint_as_float(u_ & 0xFFFF0000u);                    \
          *(unsigned short*)((char*)z_lo + byte_) = (unsigned short)(__float_as_uint(lo_) >> 16); \
        }                                                                        \
      }                                                                          \
    }                                                                            \
  } while (0)

#define PHASE_B(SLICE)                                                           \
  do {                                                                           \
    const unsigned short* qh0_ = Wt + OFF_WIN_HI + cr0 * 512 + (SLICE) * 128 + c0 * 8; \
    const unsigned short* ql0_ = Wt + OFF_WIN_LO + cr0 * 512 + (SLICE) * 128 + c0 * 8; \
    const unsigned short* qh1_ = Wt + OFF_WIN_HI + cr1 * 512 + (SLICE) * 128 + c0 * 8; \
    const unsigned short* ql1_ = Wt + OFF_WIN_LO + cr1 * 512 + (SLICE) * 128 + c0 * 8; \
    uint4 wA0_ = *(const uint4*)(qh0_), wA1_ = *(const uint4*)(ql0_);            \
    uint4 wA2_ = *(const uint4*)(qh1_), wA3_ = *(const uint4*)(ql1_);            \
    uint4 wB0_, wB1_, wB2_, wB3_;                                                \
    STORE_BT(wA0_, wA1_, wA2_, wA3_);                                            \
    lgkm0_barrier();                                                             \
    wB0_ = *(const uint4*)(qh0_ + 32); wB1_ = *(const uint4*)(ql0_ + 32);        \
    wB2_ = *(const uint4*)(qh1_ + 32); wB3_ = *(const uint4*)(ql1_ + 32);        \
    MFMA_B(0);                                                                   \
    fence_barrier();                                                             \
    STORE_BT(wB0_, wB1_, wB2_, wB3_);                                            \
    lgkm0_barrier();                                                             \
    wA0_ = *(const uint4*)(qh0_ + 64); wA1_ = *(const uint4*)(ql0_ + 64);        \
    wA2_ = *(const uint4*)(qh1_ + 64); wA3_ = *(const uint4*)(ql1_ + 64);        \
    MFMA_B(1);                                                                   \
    fence_barrier();                                                             \
    STORE_BT(wA0_, wA1_, wA2_, wA3_);                                            \
    lgkm0_barrier();                                                             \
    wB0_ = *(const uint4*)(qh0_ + 96); wB1_ = *(const uint4*)(ql0_ + 96);        \
    wB2_ = *(const uint4*)(qh1_ + 96); wB3_ = *(const uint4*)(ql1_ + 96);        \
    MFMA_B(2);                                                                   \
    fence_barrier();                                                             \
    STORE_BT(wB0_, wB1_, wB2_, wB3_);                                            \
    lgkm0_barrier();                                                             \
    MFMA_B(3);                                                                   \
    fence_barrier();                                                             \
  } while (0)

  f32x4 hacc[2][8];
#pragma unroll
  for (int a = 0; a < 2; ++a)
#pragma unroll
    for (int b = 0; b < 8; ++b) hacc[a][b] = (f32x4)0.f;

  // ---- big segments: des (s=0), tweet (s=1); K=768 = 24 K-tiles, pipelined ----
#pragma unroll
  for (int s = 0; s < 2; ++s) {
    const int off = (s == 0) ? 785 : 6;
    const unsigned short* wh = Wt + (s == 0 ? OFF_DES_HI : OFF_TW_HI);
    const unsigned short* wl = Wt + (s == 0 ? OFF_DES_LO : OFF_TW_LO);
    const float* bias = (s == 0) ? bdes : btw;

    const float* xr0 = xrow0 + off + lg * 8;
    const float* xr1 = xrow1 + off + lg * 8;
    const unsigned short* ph0 = wh + cr0 * 768 + c0 * 8;
    const unsigned short* pl0 = wl + cr0 * 768 + c0 * 8;
    const unsigned short* ph1 = wh + cr1 * 768 + c0 * 8;
    const unsigned short* pl1 = wl + cr1 * 768 + c0 * 8;

    f32x4 zacc[2][8];
#pragma unroll
    for (int a = 0; a < 2; ++a)
#pragma unroll
      for (int b = 0; b < 8; ++b) zacc[a][b] = (f32x4)0.f;

    uint4 WA0, WA1, WA2, WA3, WB0, WB1, WB2, WB3;
    f32x4u X0a0, X0b0, X0a1, X0b1, X1a0, X1b0, X1a1, X1b1;

    // prologue: W tile 0, X tiles 0..1 (depth-2 ping-pong)
    WA0 = *(const uint4*)(ph0); WA1 = *(const uint4*)(pl0);
    WA2 = *(const uint4*)(ph1); WA3 = *(const uint4*)(pl1);
    X0a0 = *(const f32x4u*)(xr0);      X0b0 = *(const f32x4u*)(xr0 + 4);
    X0a1 = *(const f32x4u*)(xr1);      X0b1 = *(const f32x4u*)(xr1 + 4);
    X1a0 = *(const f32x4u*)(xr0 + 32); X1b0 = *(const f32x4u*)(xr0 + 36);
    X1a1 = *(const f32x4u*)(xr1 + 32); X1b1 = *(const f32x4u*)(xr1 + 36);

    for (int base = 0; base < 24; base += 2) {
      TILE(WA0, WA1, WA2, WA3, WB0, WB1, WB2, WB3, X0a0, X0b0, X0a1, X0b1, base + 0);
      TILE(WB0, WB1, WB2, WB3, WA0, WA1, WA2, WA3, X1a0, X1b0, X1a1, X1b1, base + 1);
    }
    Z_EPI(zacc, bias);   // z slots are wave-private
    PHASE_B(s);
  }

  // ---- small segments: num (K=6), cat (K=11); single padded K-tile each ----
#pragma unroll
  for (int u = 0; u < 2; ++u) {
    const int offu = (u == 0) ? 0 : 774;
    const int Ksu = (u == 0) ? 6 : 11;
    const unsigned short* wh = Wt + (u == 0 ? OFF_NUM_HI : OFF_CAT_HI);
    const unsigned short* wl = Wt + (u == 0 ? OFF_NUM_LO : OFF_CAT_LO);
    const float* biasu = (u == 0) ? bnum : bcat;
    const float* xr0 = xrow0 + offu + lg * 8;
    const float* xr1 = xrow1 + offu + lg * 8;

    uint4 s0 = *(const uint4*)(wh + cr0 * 32 + c0 * 8);
    uint4 s1 = *(const uint4*)(wl + cr0 * 32 + c0 * 8);
    uint4 s2 = *(const uint4*)(wh + cr1 * 32 + c0 * 8);
    uint4 s3 = *(const uint4*)(wl + cr1 * 32 + c0 * 8);
    f32x4u fa0 = *(const f32x4u*)(xr0);
    f32x4u fb0 = *(const f32x4u*)(xr0 + 4);
    f32x4u fa1 = *(const f32x4u*)(xr1);
    f32x4u fb1 = *(const f32x4u*)(xr1 + 4);
#pragma unroll
    for (int j = 0; j < 4; ++j) {
      if (lg * 8 + j >= Ksu) { fa0[j] = 0.f; fa1[j] = 0.f; }
      if (lg * 8 + 4 + j >= Ksu) { fb0[j] = 0.f; fb1[j] = 0.f; }
    }

    f32x4 zacc[2][8];
#pragma unroll
    for (int a = 0; a < 2; ++a)
#pragma unroll
      for (int b = 0; b < 8; ++b) zacc[a][b] = (f32x4)0.f;

    STORE_BT(s0, s1, s2, s3);
    lgkm0_barrier();
    {
      Frag a0h_, a0l_, a1h_, a1l_;
      CVT_A2(fa0, fb0, a0h_, a0l_);
      CVT_A2(fa1, fb1, a1h_, a1l_);
      MFMA8_2(a0h_, a0l_, a1h_, a1l_, zacc);
    }
    fence_barrier();
    Z_EPI(zacc, biasu);
    PHASE_B(u + 2);
  }

  // epilogue: + b_in, PReLU, store (f32 + RNE-bf16 copy for the gather)
#pragma unroll
  for (int ct = 0; ct < 8; ++ct) {
    int col = ct * 16 + li;
    float bi = bin[col];
    float p = pa[col];
#pragma unroll
    for (int sub = 0; sub < 2; ++sub) {
#pragma unroll
      for (int r = 0; r < 4; ++r) {
        int node = node0 + w * 32 + sub * 16 + lg * 4 + r;
        if (node < NN) {
          float v = hacc[sub][ct][r] + bi;
          v = v >= 0.f ? v : p * v;
          h0[(size_t)node * HD + col] = v;
          h16[(size_t)node * HD + col] = bf16_rne(v);
        }
      }
    }
  }

#undef TILE
#undef MFMA_B
#undef Z_EPI
#undef PHASE_B
#undef MFMA8_2
#undef CVT_A2
#undef STORE_BT
}

// ---------------- neighbor-mean gather (bf16 in, bf16 out) ----------------------
__global__ __launch_bounds__(256) void k_gather(
    const unsigned short* __restrict__ h16, unsigned short* __restrict__ agg16,
    const int* __restrict__ row_ptr, const int* __restrict__ cnt2,
    const int* __restrict__ entries) {
  int i = blockIdx.x * 4 + (threadIdx.x >> 6);
  int l = threadIdx.x & 63;
  if (i >= NN) return;
  int rs = row_ptr[i], re = row_ptr[i + 1];
  int c0 = cnt2[i], c1 = cnt2[NN + i];
  float inv0 = 1.f / (float)(c0 > 0 ? c0 : 1);
  float inv1 = 1.f / (float)(c1 > 0 ? c1 : 1);
  float a0 = 0, a1 = 0, b0 = 0, b1 = 0;
  int e = rs;
  for (; e + 3 < re; e += 4) {
    int ent0 = entries[e], ent1 = entries[e + 1];
    int ent2 = entries[e + 2], ent3 = entries[e + 3];
    unsigned int p0 = ((const unsigned int*)(h16 + (size_t)(ent0 & 0xFFFFF) * HD))[l];
    unsigned int p1 = ((const unsigned int*)(h16 + (size_t)(ent1 & 0xFFFFF) * HD))[l];
    unsigned int p2 = ((const unsigned int*)(h16 + (size_t)(ent2 & 0xFFFFF) * HD))[l];
    unsigned int p3 = ((const unsigned int*)(h16 + (size_t)(ent3 & 0xFFFFF) * HD))[l];
    float v0x = __uint_as_float(p0 << 16), v0y = __uint_as_float(p0 & 0xFFFF0000u);
    float v1x = __uint_as_float(p1 << 16), v1y = __uint_as_float(p1 & 0xFFFF0000u);
    float v2x = __uint_as_float(p2 << 16), v2y = __uint_as_float(p2 & 0xFFFF0000u);
    float v3x = __uint_as_float(p3 << 16), v3y = __uint_as_float(p3 & 0xFFFF0000u);
    if (ent0 >> 20) { b0 += v0x; b1 += v0y; } else { a0 += v0x; a1 += v0y; }
    if (ent1 >> 20) { b0 += v1x; b1 += v1y; } else { a0 += v1x; a1 += v1y; }
    if (ent2 >> 20) { b0 += v2x; b1 += v2y; } else { a0 += v2x; a1 += v2y; }
    if (ent3 >> 20) { b0 += v3x; b1 += v3y; } else { a0 += v3x; a1 += v3y; }
  }
  for (; e < re; ++e) {
    int ent = entries[e];
    unsigned int p0 = ((const unsigned int*)(h16 + (size_t)(ent & 0xFFFFF) * HD))[l];
    float v0x = __uint_as_float(p0 << 16), v0y = __uint_as_float(p0 & 0xFFFF0000u);
    if (ent >> 20) { b0 += v0x; b1 += v0y; } else { a0 += v0x; a1 += v0y; }
  }
  // pack: even col (2l) low half, odd col (2l+1) high half — matches cvt_pair order
  unsigned int* q0 = (unsigned int*)(agg16 + (size_t)i * HD);
  unsigned int* q1 = (unsigned int*)(agg16 + (size_t)NN * HD + (size_t)i * HD);
  q0[l] = (unsigned int)bf16_rne(a0 * inv0) | ((unsigned int)bf16_rne(a1 * inv0) << 16);
  q1[l] = (unsigned int)bf16_rne(b0 * inv1) | ((unsigned int)bf16_rne(b1 * inv1) << 16);
}

// ---------------- fused layer GEMM: out = [h|agg0|agg1] @ [root;rel0;rel1] + b ---
// kt 0-3: hin (f32, split-bf16, 3 MFMAs/tile). kt 4-11: agg16 (bf16 A-operand,
// A_lo = 0 exactly => al*bh MFMA dropped: 2 MFMAs/tile, bit-identical).
__global__ __launch_bounds__(256, 4) void k_rgemm2(
    const float* __restrict__ hin, const unsigned short* __restrict__ agg16,
    const unsigned short* __restrict__ wl_hi, const unsigned short* __restrict__ wl_lo,
    const float* __restrict__ bias, float* __restrict__ outp,
    unsigned short* __restrict__ h16out) {
  __shared__ unsigned short bt_hi[128 * 32], bt_lo[128 * 32];   // 8KB + 8KB

  const int t = threadIdx.x;
  const int node0 = blockIdx.x * 64;
  const int w = t >> 6, lane = t & 63;
  const int li = lane & 15, lg = lane >> 4;

  const int cr0 = t >> 2, c0 = t & 3;
  const int cr1 = cr0 + 64;
  const unsigned stb0 = cr0 * 64 + ((c0 ^ ((cr0 >> 1) & 3)) << 4);
  const unsigned stb1 = cr1 * 64 + ((c0 ^ ((cr1 >> 1) & 3)) << 4);

  const int rowA = w * 16 + li;
  int nodeA = node0 + rowA;
  int ndA = nodeA < NN ? nodeA : NN - 1;
  const float* a0p = hin + (size_t)ndA * HD + lg * 8;
  const unsigned short* g0p = agg16 + (size_t)ndA * HD + lg * 8;
  const unsigned short* g1p = agg16 + (size_t)NN * HD + (size_t)ndA * HD + lg * 8;

#define STORE_BT(SH0, SL0, SH1, SL1)              \
  do {                                            \
    *(uint4*)((char*)bt_hi + stb0) = (SH0);       \
    *(uint4*)((char*)bt_lo + stb0) = (SL0);       \
    *(uint4*)((char*)bt_hi + stb1) = (SH1);       \
    *(uint4*)((char*)bt_lo + stb1) = (SL1);       \
  } while (0)

#define CVT_A2(FA, FB, AH, AL)                                                   \
  do {                                                                           \
    cvt_pair((FA)[0], (FA)[1], (AH).u[0], (AL).u[0]);                            \
    cvt_pair((FA)[2], (FA)[3], (AH).u[1], (AL).u[1]);                            \
    cvt_pair((FB)[0], (FB)[1], (AH).u[2], (AL).u[2]);                            \
    cvt_pair((FB)[2], (FB)[3], (AH).u[3], (AL).u[3]);                            \
  } while (0)

// split path: 3 MFMAs per col-tile
#define MFMA8F(AH, AL)                                                           \
  do {                                                                           \
    _Pragma("unroll")                                                            \
    for (int ct_ = 0; ct_ < 8; ++ct_) {                                          \
      int colrow_ = ct_ * 16 + li;                                               \
      int byte_ = colrow_ * 64 + (lg << 4);                                      \
      byte_ ^= ((colrow_ >> 1) & 3) << 4;                                        \
      Frag bh_, bl_;                                                             \
      bh_.v = *(const uint4*)((char*)bt_hi + byte_);                             \
      bl_.v = *(const uint4*)((char*)bt_lo + byte_);                             \
      acc[ct_] = __builtin_amdgcn_mfma_f32_16x16x32_bf16((AH).s, bl_.s, acc[ct_], 0, 0, 0); \
      acc[ct_] = __builtin_amdgcn_mfma_f32_16x16x32_bf16((AL).s, bh_.s, acc[ct_], 0, 0, 0); \
      acc[ct_] = __builtin_amdgcn_mfma_f32_16x16x32_bf16((AH).s, bh_.s, acc[ct_], 0, 0, 0); \
    }                                                                            \
  } while (0)

// bf16-A path: A_lo == 0 exactly -> 2 MFMAs per col-tile (bit-identical)
#define MFMA8H(AH)                                                               \
  do {                                                                           \
    _Pragma("unroll")                                                            \
    for (int ct_ = 0; ct_ < 8; ++ct_) {                                          \
      int colrow_ = ct_ * 16 + li;                                               \
      int byte_ = colrow_ * 64 + (lg << 4);                                      \
      byte_ ^= ((colrow_ >> 1) & 3) << 4;                                        \
      Frag bh_, bl_;                                                             \
      bh_.v = *(const uint4*)((char*)bt_hi + byte_);                             \
      bl_.v = *(const uint4*)((char*)bt_lo + byte_);                             \
      acc[ct_] = __builtin_amdgcn_mfma_f32_16x16x32_bf16((AH).s, bl_.s, acc[ct_], 0, 0, 0); \
      acc[ct_] = __builtin_amdgcn_mfma_f32_16x16x32_bf16((AH).s, bh_.s, acc[ct_], 0, 0, 0); \
    }                                                                            \
  } while (0)

#define W2H(KT, CR) (wl_hi + ((KT) >> 2) * 16384 + (CR) * 128 + ((KT) & 3) * 32 + c0 * 8)
#define W2L(KT, CR) (wl_lo + ((KT) >> 2) * 16384 + (CR) * 128 + ((KT) & 3) * 32 + c0 * 8)
// bf16 agg A source for local tile j (0..7): rel0 j 0..3, rel1 j 4..7
#define GSRC(J) ((J) < 4 ? (g0p + (J) * 32) : (g1p + ((J) - 4) * 32))

  f32x4 acc[8];
#pragma unroll
  for (int b = 0; b < 8; ++b) acc[b] = (f32x4)0.f;

  uint4 WA0, WA1, WA2, WA3, WB0, WB1, WB2, WB3;
  f32x4u X0a, X0b, X1a, X1b, X2a, X2b;
  uint4 Y0, Y1;

  // prologue: W tile 0, hin tiles 0..2
  WA0 = *(const uint4*)W2H(0, cr0); WA1 = *(const uint4*)W2L(0, cr0);
  WA2 = *(const uint4*)W2H(0, cr1); WA3 = *(const uint4*)W2L(0, cr1);
  X0a = *(const f32x4u*)(a0p);      X0b = *(const f32x4u*)(a0p + 4);
  X1a = *(const f32x4u*)(a0p + 32); X1b = *(const f32x4u*)(a0p + 36);
  X2a = *(const f32x4u*)(a0p + 64); X2b = *(const f32x4u*)(a0p + 68);

  // ---- f32 section: kt 0..3 ----
  STORE_BT(WA0, WA1, WA2, WA3);
  lgkm0_barrier();
  {
    Frag ah_, al_;
    CVT_A2(X0a, X0b, ah_, al_);
    WB0 = *(const uint4*)W2H(1, cr0); WB1 = *(const uint4*)W2L(1, cr0);
    WB2 = *(const uint4*)W2H(1, cr1); WB3 = *(const uint4*)W2L(1, cr1);
    X0a = *(const f32x4u*)(a0p + 96); X0b = *(const f32x4u*)(a0p + 100);
    MFMA8F(ah_, al_);
  }
  fence_barrier();
  STORE_BT(WB0, WB1, WB2, WB3);
  lgkm0_barrier();
  {
    Frag ah_, al_;
    CVT_A2(X1a, X1b, ah_, al_);
    WA0 = *(const uint4*)W2H(2, cr0); WA1 = *(const uint4*)W2L(2, cr0);
    WA2 = *(const uint4*)W2H(2, cr1); WA3 = *(const uint4*)W2L(2, cr1);
    Y0 = *(const uint4*)GSRC(0);
    MFMA8F(ah_, al_);
  }
  fence_barrier();
  STORE_BT(WA0, WA1, WA2, WA3);
  lgkm0_barrier();
  {
    Frag ah_, al_;
    CVT_A2(X2a, X2b, ah_, al_);
    WB0 = *(const uint4*)W2H(3, cr0); WB1 = *(const uint4*)W2L(3, cr0);
    WB2 = *(const uint4*)W2H(3, cr1); WB3 = *(const uint4*)W2L(3, cr1);
    Y1 = *(const uint4*)GSRC(1);
    MFMA8F(ah_, al_);
  }
  fence_barrier();
  STORE_BT(WB0, WB1, WB2, WB3);
  lgkm0_barrier();
  {
    Frag ah_, al_;
    CVT_A2(X0a, X0b, ah_, al_);
    WA0 = *(const uint4*)W2H(4, cr0); WA1 = *(const uint4*)W2L(4, cr0);
    WA2 = *(const uint4*)W2H(4, cr1); WA3 = *(const uint4*)W2L(4, cr1);
    MFMA8F(ah_, al_);
  }
  fence_barrier();

  // ---- bf16 agg section: local tiles 0..7 (kt 4..11), Y ping-pong depth-2 ----
#define TILEB(WC0, WC1, WC2, WC3, WN0, WN1, WN2, WN3, YB, J)                     \
  do {                                                                           \
    STORE_BT(WC0, WC1, WC2, WC3);                                                \
    lgkm0_barrier();                                                             \
    Frag ah_;                                                                    \
    ah_.v = (YB);                                                                \
    {                                                                            \
      int kn_ = (J) + 5; if (kn_ > 11) kn_ = 11;                                 \
      WN0 = *(const uint4*)W2H(kn_, cr0); WN1 = *(const uint4*)W2L(kn_, cr0);    \
      WN2 = *(const uint4*)W2H(kn_, cr1); WN3 = *(const uint4*)W2L(kn_, cr1);    \
      int jy_ = (J) + 2; if (jy_ > 7) jy_ = 7;                                   \
      (YB) = *(const uint4*)GSRC(jy_);                                           \
    }                                                                            \
    MFMA8H(ah_);                                                                 \
    fence_barrier();                                                             \
  } while (0)

  TILEB(WA0, WA1, WA2, WA3, WB0, WB1, WB2, WB3, Y0, 0);
  TILEB(WB0, WB1, WB2, WB3, WA0, WA1, WA2, WA3, Y1, 1);
  TILEB(WA0, WA1, WA2, WA3, WB0, WB1, WB2, WB3, Y0, 2);
  TILEB(WB0, WB1, WB2, WB3, WA0, WA1, WA2, WA3, Y1, 3);
  TILEB(WA0, WA1, WA2, WA3, WB0, WB1, WB2, WB3, Y0, 4);
  TILEB(WB0, WB1, WB2, WB3, WA0, WA1, WA2, WA3, Y1, 5);
  TILEB(WA0, WA1, WA2, WA3, WB0, WB1, WB2, WB3, Y0, 6);
  TILEB(WB0, WB1, WB2, WB3, WA0, WA1, WA2, WA3, Y1, 7);

  // epilogue: + bias, store (and optional bf16 copy)
#pragma unroll
  for (int ct = 0; ct < 8; ++ct) {
    int col = ct * 16 + li;
    float bv = bias[col];
#pragma unroll
    for (int r = 0; r < 4; ++r) {
      int node = node0 + w * 16 + lg * 4 + r;
      if (node < NN) {
        float v = acc[ct][r] + bv;
        outp[(size_t)node * HD + col] = v;
        if (h16out) h16out[(size_t)node * HD + col] = bf16_rne(v);
      }
    }
  }

#undef TILEB
#undef GSRC
#undef W2H
#undef W2L
#undef MFMA8H
#undef MFMA8F
#undef CVT_A2
#undef STORE_BT
}

extern "C" void kernel_launch(void* const* d_in, const int* in_sizes, int n_in,
                              void* d_out, int out_size, void* d_ws, size_t ws_size,
                              hipStream_t stream) {
  const float* x    = (const float*)d_in[0];
  const int* ei     = (const int*)d_in[1];
  const int* et     = (const int*)d_in[2];
  const float* Wdes = (const float*)d_in[3];
  const float* bdes = (const float*)d_in[4];
  const float* Wtw  = (const float*)d_in[5];
  const float* btw  = (const float*)d_in[6];
  const float* Wnum = (const float*)d_in[7];
  const float* bnum = (const float*)d_in[8];
  const float* Wcat = (const float*)d_in[9];
  const float* bcat = (const float*)d_in[10];
  const float* Win  = (const float*)d_in[11];
  const float* bin  = (const float*)d_in[12];
  const float* pa   = (const float*)d_in[13];
  const float* root1 = (const float*)d_in[14];
  const float* rel1  = (const float*)d_in[15];
  const float* bias1 = (const float*)d_in[16];
  const float* root2 = (const float*)d_in[17];
  const float* rel2  = (const float*)d_in[18];
  const float* bias2 = (const float*)d_in[19];
  const float* Wcls  = (const float*)d_in[20];
  const float* bcls  = (const float*)d_in[21];
  float* out = (float*)d_out;

  char* p = (char*)d_ws;
  unsigned short* agg16 = (unsigned short*)p; p += (size_t)2 * NN * HD * 2;  // 51.2 MB
  float* hB = (float*)p;      p += (size_t)NN * HD * 4;       // 51.2 MB
  int* row_ptr = (int*)p;     p += ((size_t)NN + 4) * 4;
  int* cnt2 = (int*)p;        p += (size_t)2 * NN * 4;
  int* fillpos = (int*)p;     p += (size_t)NN * 4;
  int* entries = (int*)p;     p += (size_t)EE * 4;
  int* bsum = (int*)p;        p += 512;
  float* bfused = (float*)p;  p += 512;
  unsigned short* h16 = (unsigned short*)p; p += (size_t)NN * HD * 2;  // 25.6 MB
  unsigned short* Wt = (unsigned short*)p;  p += (size_t)WT_SITES * 2 * 2;

  // zero counters first (cnt2 + fillpos)
  (void)hipMemsetAsync(cnt2, 0, (size_t)3 * NN * 4, stream);
  // setup: weight pre-convert + edge count + classifier fusion, one launch
  k_setup<<<PREPW_BLOCKS + COUNT_BLOCKS + FUSEW_BLOCKS, 256, 0, stream>>>(
      Wdes, Wtw, Wnum, Wcat, Win, root1, rel1, root2, rel2, Wcls, Wt,
      ei, et, cnt2, bias2, bcls, bfused);

  // CSR scans
  int nb = (NN + 1023) / 1024;
  k_scan1<<<nb, 256, 0, stream>>>(cnt2, row_ptr, bsum);
  k_scan2<<<1, 128, 0, stream>>>(bsum, nb);
  k_scan3<<<(NN + 1 + 255) / 256, 256, 0, stream>>>(row_ptr, bsum);

  // h0 -> d_out (+ h16 bf16 copy), with CSR fill fused in (blocks >= PROJ128_NBLK)
  k_proj2<<<PROJ128_NBLK + FILL_BLOCKS, 256, 0, stream>>>(
      x, bdes, btw, bnum, bcat, bin, pa, Wt, out, h16,
      ei, et, row_ptr, fillpos, entries);
  // layer 1: gather neighbor means (bf16 in/out), then fused K=384 GEMM -> hB
  k_gather<<<NN / 4, 256, 0, stream>>>(h16, agg16, row_ptr, cnt2, entries);
  k_rgemm2<<<NBLK64, 256, 0, stream>>>(out, agg16, Wt + OFF_L1_HI, Wt + OFF_L1_LO,
                                       bias1, hB, h16);
  // layer 2 + classifier (algebraically fused): out = [hB|agg] @ (W2@Wcls) + bfused
  k_gather<<<NN / 4, 256, 0, stream>>>(h16, agg16, row_ptr, cnt2, entries);
  k_rgemm2<<<NBLK64, 256, 0, stream>>>(hB, agg16, Wt + OFF_L2_HI, Wt + OFF_L2_LO,
                                       bfused, out, (unsigned short*)nullptr);
}